// Round 1
// baseline (137.669 us; speedup 1.0000x reference)
//
#include <hip/hip_runtime.h>

#define NTREE  64
#define NFEAT  1024
#define NLEAF  64
#define NBATCH 32768
#define WAVES  4
#define THREADS 256

// Tree semantics (from reference):
//   d[j] = sigmoid(x[b, fidx[t, j]])
//   layer k (k=0..5): parent i (of 2^k) uses d[(2^k - 1) + i];
//     child 2i gets *d, child 2i+1 gets *(1-d)
//   prob[b,t]   = sum_l mu[l] * pi[t,l]
//   probs[b,l,t] = mu[b,t,l]   (transposed output)
__global__ __launch_bounds__(THREADS)
void forest_kernel(const float* __restrict__ x,
                   const int*   __restrict__ fidx,
                   const float* __restrict__ pi,
                   float* __restrict__ prob,    // [B][T]
                   float* __restrict__ probs)   // [B][L][T]
{
    __shared__ float srow[WAVES][NFEAT];     // sigmoid of one x-row per wave (16 KB)
    __shared__ int   idxl[NTREE * 63];       // feature indices            (15.75 KB)
    __shared__ float pil[NTREE * 65];        // pi, padded stride 65       (16.25 KB)

    const int tid  = threadIdx.x;
    const int wid  = tid >> 6;
    const int lane = tid & 63;               // lane == tree index t

    // Stage fidx and pi once per block (L2-resident, cheap).
    for (int i = tid; i < NTREE * 63; i += THREADS) idxl[i] = fidx[i];
    for (int i = tid; i < NTREE * NLEAF; i += THREADS)
        pil[(i >> 6) * 65 + (i & 63)] = pi[i];
    __syncthreads();

    const int wavestride = gridDim.x * WAVES;
    for (int b = blockIdx.x * WAVES + wid; b < NBATCH; b += wavestride) {
        // ---- Stage sigmoid(x[b,:]) into this wave's LDS row (float4 loads) ----
        const float4* xr4 = reinterpret_cast<const float4*>(x + (size_t)b * NFEAT);
        float4* sr4 = reinterpret_cast<float4*>(&srow[wid][0]);
        #pragma unroll
        for (int i = 0; i < NFEAT / (64 * 4); ++i) {
            float4 v = xr4[lane + i * 64];
            float4 s;
            s.x = 1.0f / (1.0f + __expf(-v.x));
            s.y = 1.0f / (1.0f + __expf(-v.y));
            s.z = 1.0f / (1.0f + __expf(-v.z));
            s.w = 1.0f / (1.0f + __expf(-v.w));
            sr4[lane + i * 64] = s;
        }
        __syncthreads();

        const int t = lane;
        const float* sw = &srow[wid][0];
        const int ib = t * 63;

        // ---- Layers 0..4: in-place doubling, mu[0..31] = level-5 interior probs ----
        float mu[32];
        mu[0] = 1.0f;
        #pragma unroll
        for (int k = 0; k < 5; ++k) {
            const int n = 1 << k;
            #pragma unroll
            for (int i = n - 1; i >= 0; --i) {
                float dv = sw[idxl[ib + (n - 1) + i]];
                float m  = mu[i];
                float a  = m * dv;
                mu[2 * i]     = a;        // child 2i:   * d
                mu[2 * i + 1] = m - a;    // child 2i+1: * (1-d)
            }
        }

        // ---- Final layer fused with store + pi-dot epilogue ----
        float acc = 0.0f;
        float* pb = probs + (size_t)b * (NLEAF * NTREE) + t;
        const int ip = t * 65;
        #pragma unroll
        for (int i = 0; i < 32; ++i) {
            float dv = sw[idxl[ib + 31 + i]];
            float m  = mu[i];
            float a  = m * dv;      // leaf 2i
            float c  = m - a;       // leaf 2i+1
            pb[(2 * i) * NTREE]     = a;   // coalesced: 64 lanes span t
            pb[(2 * i + 1) * NTREE] = c;
            acc = fmaf(a, pil[ip + 2 * i], acc);
            acc = fmaf(c, pil[ip + 2 * i + 1], acc);
        }
        prob[b * NTREE + t] = acc;
        __syncthreads();   // srow[wid] reused next row; uniform trip count
    }
}

extern "C" void kernel_launch(void* const* d_in, const int* in_sizes, int n_in,
                              void* d_out, int out_size, void* d_ws, size_t ws_size,
                              hipStream_t stream) {
    const float* x    = (const float*)d_in[0];
    const int*   fidx = (const int*)d_in[1];
    const float* pi   = (const float*)d_in[2];
    float* prob  = (float*)d_out;                              // B*T
    float* probs = (float*)d_out + (size_t)NBATCH * NTREE;     // B*L*T

    dim3 grid(2048), block(THREADS);
    hipLaunchKernelGGL(forest_kernel, grid, block, 0, stream,
                       x, fidx, pi, prob, probs);
}